// Round 9
// baseline (151.604 us; speedup 1.0000x reference)
//
#include <hip/hip_runtime.h>
#include <hip/hip_bf16.h>

// Problem constants (fixed by setup_inputs): B=64, T=1024, C=768, CK=64, R=256
#define BB 64
#define TT 1024
#define CC 768
#define CKK 64
#define SS 512   // T/2
#define RR 256
#define TOUT 768 // R + S
#define ASTRIDE 68  // 64 + 4 pad: 16B-aligned, stride mod 32 = 4 -> 2-way max
#define NSCORE (BB * 8)       // 512 score blocks
#define NCOPY  (BB * SS / 4)  // 8192 copy blocks (wave per row, 4 rows/block)

typedef float v4f __attribute__((ext_vector_type(4)));

// ---------------------------------------------------------------------------
// Kernel 1 (fused by block range), one dispatch:
//  [0, NSCORE): register-tiled max-GEMM scores[s,d]=dot(k[2s],k[2d+1]);
//    XCD-clustered (blockIdx%8 == batch%8). Epilogue: release-publish nodekey,
//    fetch_add(done[b], ACQ_REL); the 8th arriver REUSES its block (and dead
//    LDS) to sort batch b in place — no spinning anywhere.
//  [NSCORE, ...): dst-base copy out[b][R+d] = x[b][2d+1] (NT float4), wave/row.
// Sorter output: unm_idx, per-dst dstinfo = cnt|e0<<9|off<<18, CSR src array,
// plus compacted worklist wd[] of dsts with cnt>0 and counts nchain[b].
// ---------------------------------------------------------------------------
__global__ __launch_bounds__(256) void score_copy_sort_kernel(
    const float* __restrict__ k, const float* __restrict__ x,
    float* __restrict__ out, unsigned long long* __restrict__ nodekey,
    int* __restrict__ done, int* __restrict__ unm_idx,
    int* __restrict__ dstinfo, int* __restrict__ csr,
    int* __restrict__ wd, int* __restrict__ nchain) {
  const int bid = blockIdx.x;
  const int t = threadIdx.x;

  __shared__ __align__(16) char smem[52224];

  if (bid >= NSCORE) {
    // ---------------- dst-base copy path ----------------
    const int w = t >> 6, l = t & 63;
    const int rowg = (bid - NSCORE) * 4 + w;
    const int b = rowg >> 9;
    const int d = rowg & 511;
    const v4f* s = (const v4f*)(x + ((size_t)b * TT + 2 * d + 1) * CC);
    v4f* dst = (v4f*)(out + ((size_t)b * TOUT + RR + d) * CC);
    v4f a0 = __builtin_nontemporal_load(s + l);
    v4f a1 = __builtin_nontemporal_load(s + l + 64);
    v4f a2 = __builtin_nontemporal_load(s + l + 128);
    __builtin_nontemporal_store(a0, dst + l);
    __builtin_nontemporal_store(a1, dst + l + 64);
    __builtin_nontemporal_store(a2, dst + l + 128);
    return;
  }

  // ---------------- score path ----------------
  // batch-clustered remap: bid = (b/8)*64 + rt*8 + (b%8) -> bid%8 = b%8
  const int low3 = bid & 7;
  const int g = bid >> 3;
  const int rt = g & 7;
  const int b = (g >> 3) * 8 + low3;
  const int tx = t & 15, ty = t >> 4;

  float* As = (float*)smem;             // 64*68*4  = 17408
  float* Bs = (float*)(smem + 17408);   // 128*68*4 = 34816

#pragma unroll
  for (int l = 0; l < 4; ++l) {
    int f = t + l * 256;
    int row = f >> 4, c4 = f & 15;
    float4 va = ((const float4*)(k + ((size_t)b * TT + 2 * (rt * 64 + row)) * CKK))[c4];
    *(float4*)(&As[row * ASTRIDE + c4 * 4]) = va;
  }

  unsigned long long rkey[4];
#pragma unroll
  for (int i = 0; i < 4; ++i) rkey[i] = 0ull;

  for (int ct = 0; ct < 4; ++ct) {
    __syncthreads();
#pragma unroll
    for (int l = 0; l < 8; ++l) {
      int f = t + l * 256;
      int row = f >> 4, c4 = f & 15;
      float4 vb = ((const float4*)(k + ((size_t)b * TT + 2 * (ct * 128 + row) + 1) * CKK))[c4];
      *(float4*)(&Bs[row * ASTRIDE + c4 * 4]) = vb;
    }
    __syncthreads();

    float acc[4][8];
#pragma unroll
    for (int i = 0; i < 4; ++i)
#pragma unroll
      for (int j = 0; j < 8; ++j) acc[i][j] = 0.f;

    for (int k4 = 0; k4 < 16; ++k4) {
      float4 av[4], bv[8];
#pragma unroll
      for (int i = 0; i < 4; ++i)
        av[i] = *(const float4*)(&As[(ty + 16 * i) * ASTRIDE + k4 * 4]);
#pragma unroll
      for (int j = 0; j < 8; ++j)
        bv[j] = *(const float4*)(&Bs[(tx + 16 * j) * ASTRIDE + k4 * 4]);
#pragma unroll
      for (int i = 0; i < 4; ++i)
#pragma unroll
        for (int j = 0; j < 8; ++j) {
          acc[i][j] += av[i].x * bv[j].x;
          acc[i][j] += av[i].y * bv[j].y;
          acc[i][j] += av[i].z * bv[j].z;
          acc[i][j] += av[i].w * bv[j].w;
        }
    }

#pragma unroll
    for (int i = 0; i < 4; ++i) {
      float mx = acc[i][0];
      int mj = 0;
#pragma unroll
      for (int j = 1; j < 8; ++j)
        if (acc[i][j] > mx) { mx = acc[i][j]; mj = j; }  // asc d: > keeps min d
      int d = ct * 128 + tx + 16 * mj;
      unsigned int u = __float_as_uint(mx);
      unsigned int mapped = (u & 0x80000000u) ? ~u : (u | 0x80000000u);
      unsigned long long key =
          ((unsigned long long)mapped << 32) | (unsigned int)(SS - 1 - d);
      if (key > rkey[i]) rkey[i] = key;
    }
  }

#pragma unroll
  for (int i = 0; i < 4; ++i) {
#pragma unroll
    for (int off = 1; off < 16; off <<= 1) {
      unsigned long long o = __shfl_xor(rkey[i], off);
      if (o > rkey[i]) rkey[i] = o;
    }
  }
  if (tx == 0) {
#pragma unroll
    for (int i = 0; i < 4; ++i)
      nodekey[b * SS + rt * 64 + ty + 16 * i] = rkey[i];
  }
  __syncthreads();  // nodekey stores drained (vmcnt(0) before barrier)

  // ---- last-arriver election (no spin) ----
  int* flag = (int*)(smem + 51200);  // Bs region, dead now
  if (t == 0) {
    __threadfence();  // release this block's nodekey stores (agent scope)
    int old = __hip_atomic_fetch_add(&done[b], 1, __ATOMIC_ACQ_REL,
                                     __HIP_MEMORY_SCOPE_AGENT);
    *flag = (old == 7);  // ACQ_REL on old==7 syncs with all 7 prior releases
  }
  __syncthreads();
  if (!*flag) return;

  // ---------------- winner: sort batch b in this block ----------------
  unsigned long long* keyS = (unsigned long long*)smem;     // 512*8 = 4096
  int* nodeidx = (int*)(smem + 4096);                       // 512*4 = 2048
  int* headS   = (int*)(smem + 6144);                       // 512*4 = 2048
  int* nxtS    = (int*)(smem + 8192);                       // 256*4 = 1024
  int* eS      = (int*)(smem + 9216);                       // 256*4 = 1024
  int* wsum    = (int*)(smem + 10240);                      // 8*4
  int* wsumF   = (int*)(smem + 10272);                      // 8*4

  const int lane = t & 63, w = t >> 6;
  unsigned long long my0, my1;
  {
    unsigned long long nk = nodekey[b * SS + t];
    unsigned int mapped;
    int nidx;
    if (t == 0) {  // scores[:,0,:]=NEG_INF -> max=-1e30, argmax=0
      mapped = ~__float_as_uint(-1e30f);
      nidx = 0;
    } else {
      mapped = (unsigned int)(nk >> 32);
      nidx = SS - 1 - (int)(nk & 0xffffffffu);
    }
    nodeidx[t] = nidx;
    my0 = ((unsigned long long)(~mapped) << 32) | (unsigned int)t;
  }
  {
    unsigned long long nk = nodekey[b * SS + t + 256];
    unsigned int mapped = (unsigned int)(nk >> 32);
    nodeidx[t + 256] = SS - 1 - (int)(nk & 0xffffffffu);
    my1 = ((unsigned long long)(~mapped) << 32) | (unsigned int)(t + 256);
  }
  headS[t] = -1;
  headS[t + 256] = -1;

  for (int kk = 2; kk <= SS; kk <<= 1) {
    for (int j = kk >> 1; j > 0; j >>= 1) {
      unsigned long long p0, p1;
      if (j == 256) {
        p0 = my1; p1 = my0;
      } else if (j >= 64) {
        __syncthreads();
        keyS[t] = my0; keyS[t + 256] = my1;
        __syncthreads();
        p0 = keyS[t ^ j]; p1 = keyS[(t ^ j) + 256];
      } else {
        p0 = __shfl_xor(my0, j);
        p1 = __shfl_xor(my1, j);
      }
      {
        bool tm = (((t & kk) == 0) == ((t & j) == 0));
        my0 = ((p0 < my0) == tm) ? p0 : my0;
      }
      {
        int i1 = t + 256;
        bool tm = (((i1 & kk) == 0) == ((i1 & j) == 0));
        my1 = ((p1 < my1) == tm) ? p1 : my1;
      }
    }
  }

  // slot0 = rank t (src set), slot1 = rank t+256 (unm set)
  int esrc = (int)(my0 & 0xffffffffu);
  unm_idx[b * RR + t] = (int)(my1 & 0xffffffffu);
  eS[t] = esrc;
  __syncthreads();
  int dsrc = nodeidx[esrc];
  nxtS[t] = atomicExch(&headS[dsrc], t);
  __syncthreads();

  // per-dst chain counting (d0 = t, d1 = t+256)
  int cnt0 = 0;
  for (int it = headS[t]; it >= 0; it = nxtS[it]) ++cnt0;
  int cnt1 = 0;
  for (int it = headS[t + 256]; it >= 0; it = nxtS[it]) ++cnt1;
  int f0 = cnt0 > 0, f1 = cnt1 > 0;

  // inclusive scans (cnt for CSR offsets, flags for worklist compaction)
  int v0 = cnt0, v1 = cnt1, vF0 = f0, vF1 = f1;
#pragma unroll
  for (int o = 1; o < 64; o <<= 1) {
    int n0 = __shfl_up(v0, o), n1 = __shfl_up(v1, o);
    int m0 = __shfl_up(vF0, o), m1 = __shfl_up(vF1, o);
    if (lane >= o) { v0 += n0; v1 += n1; vF0 += m0; vF1 += m1; }
  }
  if (lane == 63) {
    wsum[w] = v0; wsum[4 + w] = v1;
    wsumF[w] = vF0; wsumF[4 + w] = vF1;
  }
  __syncthreads();
  if (t == 0) {
    int run = 0, runF = 0;
    for (int q = 0; q < 8; ++q) {
      int tmp = wsum[q]; wsum[q] = run; run += tmp;
      int tf = wsumF[q]; wsumF[q] = runF; runF += tf;
    }
    nchain[b] = runF;
  }
  __syncthreads();
  int off0 = wsum[w] + v0 - cnt0;
  int off1 = wsum[4 + w] + v1 - cnt1;
  int pos0 = wsumF[w] + vF0 - f0;
  int pos1 = wsumF[4 + w] + vF1 - f1;

  int j = 0;
  for (int it = headS[t]; it >= 0; it = nxtS[it]) csr[b * RR + off0 + (j++)] = eS[it];
  int e00 = (cnt0 > 0) ? eS[headS[t]] : 0;
  dstinfo[b * SS + t] = cnt0 | (e00 << 9) | (off0 << 18);
  if (f0) wd[b * RR + pos0] = t;
  j = 0;
  for (int it = headS[t + 256]; it >= 0; it = nxtS[it]) csr[b * RR + off1 + (j++)] = eS[it];
  int e01 = (cnt1 > 0) ? eS[headS[t + 256]] : 0;
  dstinfo[b * SS + t + 256] = cnt1 | (e01 << 9) | (off1 << 18);
  if (f1) wd[b * RR + pos1] = t + 256;
}

// ---------------------------------------------------------------------------
// Kernel 2: remainder assembly via compacted worklists. Wave per row, 2 rows
// per wave (MLP). Blocks [0,2048): unm copies (16384 rows). Blocks
// [2048,4096): chain rows from wd (<=16384 slots, ~78% full). All bulk
// traffic non-temporal.
// ---------------------------------------------------------------------------
__device__ __forceinline__ void unm_row(
    const float* __restrict__ x, const int* __restrict__ unm_idx,
    float* __restrict__ out, int u, int l) {
  const int b = u >> 8, p = u & 255;
  int srow = 2 * __builtin_amdgcn_readfirstlane(unm_idx[b * RR + p]);
  const v4f* s = (const v4f*)(x + ((size_t)b * TT + srow) * CC);
  v4f* dst = (v4f*)(out + ((size_t)b * TOUT + p) * CC);
  v4f a0 = __builtin_nontemporal_load(s + l);
  v4f a1 = __builtin_nontemporal_load(s + l + 64);
  v4f a2 = __builtin_nontemporal_load(s + l + 128);
  __builtin_nontemporal_store(a0, dst + l);
  __builtin_nontemporal_store(a1, dst + l + 64);
  __builtin_nontemporal_store(a2, dst + l + 128);
}

__device__ __forceinline__ void chain_row(
    const float* __restrict__ x, const int* __restrict__ dstinfo,
    const int* __restrict__ csr, const int* __restrict__ wd,
    const int* __restrict__ nchain, float* __restrict__ out, int s, int l) {
  const int b = s >> 8, i = s & 255;
  int nc = __builtin_amdgcn_readfirstlane(nchain[b]);
  if (i >= nc) return;
  int d = __builtin_amdgcn_readfirstlane(wd[b * RR + i]);
  int info = __builtin_amdgcn_readfirstlane(dstinfo[b * SS + d]);
  int cnt = info & 511;
  int e0 = (info >> 9) & 511;
  int off = (info >> 18) & 511;
  v4f* dst = (v4f*)(out + ((size_t)b * TOUT + RR + d) * CC);
  const v4f* s0 = (const v4f*)dst;                               // base (K1)
  const v4f* s1 = (const v4f*)(x + ((size_t)b * TT + 2 * e0) * CC);
  v4f a0 = __builtin_nontemporal_load(s0 + l);
  v4f a1 = __builtin_nontemporal_load(s0 + l + 64);
  v4f a2 = __builtin_nontemporal_load(s0 + l + 128);
  v4f v0 = __builtin_nontemporal_load(s1 + l);
  v4f v1 = __builtin_nontemporal_load(s1 + l + 64);
  v4f v2 = __builtin_nontemporal_load(s1 + l + 128);
  a0 += v0; a1 += v1; a2 += v2;
  for (int j = 1; j < cnt; ++j) {
    int e = __builtin_amdgcn_readfirstlane(csr[b * RR + off + j]);
    const v4f* sx = (const v4f*)(x + ((size_t)b * TT + 2 * e) * CC);
    v4f u0 = __builtin_nontemporal_load(sx + l);
    v4f u1 = __builtin_nontemporal_load(sx + l + 64);
    v4f u2 = __builtin_nontemporal_load(sx + l + 128);
    a0 += u0; a1 += u1; a2 += u2;
  }
  __builtin_nontemporal_store(a0, dst + l);
  __builtin_nontemporal_store(a1, dst + l + 64);
  __builtin_nontemporal_store(a2, dst + l + 128);
}

__global__ __launch_bounds__(256) void gather_kernel(
    const float* __restrict__ x, const int* __restrict__ unm_idx,
    const int* __restrict__ dstinfo, const int* __restrict__ csr,
    const int* __restrict__ wd, const int* __restrict__ nchain,
    float* __restrict__ out) {
  const int w = threadIdx.x >> 6;
  const int l = threadIdx.x & 63;
  if (blockIdx.x < 2048) {
    int u = blockIdx.x * 4 + w;
    unm_row(x, unm_idx, out, u, l);
    unm_row(x, unm_idx, out, u + 8192, l);
  } else {
    int s = (blockIdx.x - 2048) * 4 + w;
    chain_row(x, dstinfo, csr, wd, nchain, out, s, l);
    chain_row(x, dstinfo, csr, wd, nchain, out, s + 8192, l);
  }
}

extern "C" void kernel_launch(void* const* d_in, const int* in_sizes, int n_in,
                              void* d_out, int out_size, void* d_ws, size_t ws_size,
                              hipStream_t stream) {
  const float* x = (const float*)d_in[0];
  const float* k = (const float*)d_in[1];
  float* out = (float*)d_out;

  char* ws = (char*)d_ws;
  unsigned long long* nodekey = (unsigned long long*)(ws);  // 64*512*8 = 262144
  int* unm_idx = (int*)(ws + 262144);                       // 64*256*4 =  65536
  int* dstinfo = (int*)(ws + 327680);                       // 64*512*4 = 131072
  int* csr     = (int*)(ws + 458752);                       // 64*256*4 =  65536
  int* wd      = (int*)(ws + 524288);                       // 64*256*4 =  65536
  int* done    = (int*)(ws + 589824);                       // 64*4     =    256
  int* nchain  = (int*)(ws + 590080);                       // 64*4     =    256
                                                            // total 590336 B

  hipMemsetAsync(done, 0, BB * sizeof(int), stream);
  score_copy_sort_kernel<<<NSCORE + NCOPY, 256, 0, stream>>>(
      k, x, out, nodekey, done, unm_idx, dstinfo, csr, wd, nchain);
  gather_kernel<<<4096, 256, 0, stream>>>(x, unm_idx, dstinfo, csr, wd, nchain, out);
}

// Round 10
// 109.147 us; speedup vs baseline: 1.3890x; 1.3890x over previous
//
#include <hip/hip_runtime.h>
#include <hip/hip_bf16.h>

// Problem constants (fixed by setup_inputs): B=64, T=1024, C=768, CK=64, R=256
#define BB 64
#define TT 1024
#define CC 768
#define CKK 64
#define SS 512   // T/2
#define RR 256
#define TOUT 768 // R + S
#define ASTRIDE 68  // 64 + 4 pad: 16B-aligned, stride mod 32 = 4 -> 2-way max
#define NSCORE (BB * 8)       // 512 score blocks
#define NCOPY  (BB * SS / 4)  // 8192 copy blocks (wave per row, 4 rows/block)

typedef float v4f __attribute__((ext_vector_type(4)));

// ---------------------------------------------------------------------------
// Kernel 1 (fused by block range, NO cross-block sync — R7 structure):
//  [0, NSCORE): register-tiled max-GEMM scores[s,d]=dot(k[2s],k[2d+1]);
//    XCD-clustered (blockIdx%8 == batch%8) for B-panel L2 reuse.
//  [NSCORE, ...): dst-base copy out[b][R+d] = x[b][2d+1] (NT float4), wave/row,
//    overlapped under score's VALU time.
// ---------------------------------------------------------------------------
__global__ __launch_bounds__(256) void score_copy_kernel(
    const float* __restrict__ k, const float* __restrict__ x,
    float* __restrict__ out, unsigned long long* __restrict__ nodekey) {
  const int bid = blockIdx.x;
  const int t = threadIdx.x;

  if (bid >= NSCORE) {
    const int w = t >> 6, l = t & 63;
    const int rowg = (bid - NSCORE) * 4 + w;
    const int b = rowg >> 9;
    const int d = rowg & 511;
    const v4f* s = (const v4f*)(x + ((size_t)b * TT + 2 * d + 1) * CC);
    v4f* dst = (v4f*)(out + ((size_t)b * TOUT + RR + d) * CC);
    v4f a0 = __builtin_nontemporal_load(s + l);
    v4f a1 = __builtin_nontemporal_load(s + l + 64);
    v4f a2 = __builtin_nontemporal_load(s + l + 128);
    __builtin_nontemporal_store(a0, dst + l);
    __builtin_nontemporal_store(a1, dst + l + 64);
    __builtin_nontemporal_store(a2, dst + l + 128);
    return;
  }

  // score path: batch-clustered remap (bijective on [0,512))
  const int low3 = bid & 7;
  const int g = bid >> 3;
  const int rt = g & 7;
  const int b = (g >> 3) * 8 + low3;
  const int tx = t & 15, ty = t >> 4;

  __shared__ float As[64 * ASTRIDE];
  __shared__ float Bs[128 * ASTRIDE];

#pragma unroll
  for (int l = 0; l < 4; ++l) {
    int f = t + l * 256;
    int row = f >> 4, c4 = f & 15;
    float4 va = ((const float4*)(k + ((size_t)b * TT + 2 * (rt * 64 + row)) * CKK))[c4];
    *(float4*)(&As[row * ASTRIDE + c4 * 4]) = va;
  }

  unsigned long long rkey[4];
#pragma unroll
  for (int i = 0; i < 4; ++i) rkey[i] = 0ull;

  for (int ct = 0; ct < 4; ++ct) {
    __syncthreads();
#pragma unroll
    for (int l = 0; l < 8; ++l) {
      int f = t + l * 256;
      int row = f >> 4, c4 = f & 15;
      float4 vb = ((const float4*)(k + ((size_t)b * TT + 2 * (ct * 128 + row) + 1) * CKK))[c4];
      *(float4*)(&Bs[row * ASTRIDE + c4 * 4]) = vb;
    }
    __syncthreads();

    float acc[4][8];
#pragma unroll
    for (int i = 0; i < 4; ++i)
#pragma unroll
      for (int j = 0; j < 8; ++j) acc[i][j] = 0.f;

    for (int k4 = 0; k4 < 16; ++k4) {
      float4 av[4], bv[8];
#pragma unroll
      for (int i = 0; i < 4; ++i)
        av[i] = *(const float4*)(&As[(ty + 16 * i) * ASTRIDE + k4 * 4]);
#pragma unroll
      for (int j = 0; j < 8; ++j)
        bv[j] = *(const float4*)(&Bs[(tx + 16 * j) * ASTRIDE + k4 * 4]);
#pragma unroll
      for (int i = 0; i < 4; ++i)
#pragma unroll
        for (int j = 0; j < 8; ++j) {
          acc[i][j] += av[i].x * bv[j].x;
          acc[i][j] += av[i].y * bv[j].y;
          acc[i][j] += av[i].z * bv[j].z;
          acc[i][j] += av[i].w * bv[j].w;
        }
    }

#pragma unroll
    for (int i = 0; i < 4; ++i) {
      float mx = acc[i][0];
      int mj = 0;
#pragma unroll
      for (int j = 1; j < 8; ++j)
        if (acc[i][j] > mx) { mx = acc[i][j]; mj = j; }  // asc d: > keeps min d
      int d = ct * 128 + tx + 16 * mj;
      unsigned int u = __float_as_uint(mx);
      unsigned int mapped = (u & 0x80000000u) ? ~u : (u | 0x80000000u);
      unsigned long long key =
          ((unsigned long long)mapped << 32) | (unsigned int)(SS - 1 - d);
      if (key > rkey[i]) rkey[i] = key;
    }
  }

#pragma unroll
  for (int i = 0; i < 4; ++i) {
#pragma unroll
    for (int off = 1; off < 16; off <<= 1) {
      unsigned long long o = __shfl_xor(rkey[i], off);
      if (o > rkey[i]) rkey[i] = o;
    }
  }
  if (tx == 0) {
#pragma unroll
    for (int i = 0; i < 4; ++i)
      nodekey[b * SS + rt * 64 + ty + 16 * i] = rkey[i];
  }
}

// ---------------------------------------------------------------------------
// Kernel 2: per-batch stable descending argsort (hybrid bitonic: j<=32 via
// shfl_xor, j>=64 via LDS), then invert src->dst scatter into a CSR src array
// plus a COMPACTED worklist wd[] = d | cnt<<9 | off<<18, ordered by chain
// length DESCENDING (16-bucket counting sort) for K3 load balance.
// ---------------------------------------------------------------------------
__global__ __launch_bounds__(512) void sort_kernel(
    const unsigned long long* __restrict__ nodekey,
    int* __restrict__ unm_idx, int* __restrict__ csr,
    int* __restrict__ wd, int* __restrict__ nchain) {
  const int b = blockIdx.x;
  const int i = threadIdx.x;
  const int lane = i & 63, w = i >> 6;
  __shared__ unsigned long long key[SS];
  __shared__ int nodeidx[SS];
  __shared__ int headS[SS];
  __shared__ int nxtS[RR];
  __shared__ int eS[RR];
  __shared__ int wsum[8];
  __shared__ int bcnt[16], boff[16];

  unsigned long long nk = nodekey[b * SS + i];
  unsigned int mapped;
  int nidx;
  if (i == 0) {  // scores[:,0,:] forced to NEG_INF -> max=-1e30, argmax=0
    mapped = ~__float_as_uint(-1e30f);
    nidx = 0;
  } else {
    mapped = (unsigned int)(nk >> 32);
    nidx = SS - 1 - (int)(nk & 0xffffffffu);
  }
  nodeidx[i] = nidx;
  headS[i] = -1;
  if (i < 16) bcnt[i] = 0;
  unsigned long long my = ((unsigned long long)(~mapped) << 32) | (unsigned int)i;

  for (int kk = 2; kk <= SS; kk <<= 1) {
    for (int j = kk >> 1; j > 0; j >>= 1) {
      bool up = ((i & kk) == 0);
      bool lower = ((i & j) == 0);
      bool takeMin = (up == lower);
      unsigned long long partner;
      if (j >= 64) {
        key[i] = my;
        __syncthreads();
        partner = key[i ^ j];
        __syncthreads();
      } else {
        partner = __shfl_xor(my, j);
      }
      bool pSmaller = partner < my;
      my = (takeMin == pSmaller) ? partner : my;
    }
  }
  __syncthreads();

  int e = (int)(my & 0xffffffffu);
  if (i < RR) {
    eS[i] = e;
    int d = nodeidx[e];
    nxtS[i] = atomicExch(&headS[d], i);
  } else {
    unm_idx[b * RR + (i - RR)] = e;
  }
  __syncthreads();

  // thread i == dst row d: walk chain, count
  int cnt = 0;
  for (int it = headS[i]; it >= 0; it = nxtS[it]) ++cnt;

  // inclusive scan of cnt for CSR offsets (wave shfl + cross-wave combine)
  int v = cnt;
#pragma unroll
  for (int o = 1; o < 64; o <<= 1) {
    int n = __shfl_up(v, o);
    if (lane >= o) v += n;
  }
  if (lane == 63) wsum[w] = v;
  __syncthreads();
  if (i == 0) {
    int run = 0;
    for (int q = 0; q < 8; ++q) { int tmp = wsum[q]; wsum[q] = run; run += tmp; }
  }
  __syncthreads();
  int off = wsum[w] + v - cnt;  // exclusive

  int j = 0;
  for (int it = headS[i]; it >= 0; it = nxtS[it]) csr[b * RR + off + (j++)] = eS[it];

  // bucket worklist by cnt (desc): bucket c = min(cnt,15)
  int c = cnt < 15 ? cnt : 15;
  int pos = -1;
  if (cnt > 0) pos = atomicAdd(&bcnt[c], 1);
  __syncthreads();
  if (i == 0) {
    int run = 0;
    for (int q = 15; q >= 1; --q) { boff[q] = run; run += bcnt[q]; }
    nchain[b] = run;
  }
  __syncthreads();
  if (cnt > 0) wd[b * RR + boff[c] + pos] = i | (cnt << 9) | (off << 18);
}

// ---------------------------------------------------------------------------
// Kernel 3: remainder assembly via compacted worklist. Wave per row, 2 rows
// per wave (MLP). Blocks [0,2048): chain rows (longest chains first).
// Blocks [2048,4096): unm copies. All bulk traffic non-temporal.
// ---------------------------------------------------------------------------
__device__ __forceinline__ void unm_row(
    const float* __restrict__ x, const int* __restrict__ unm_idx,
    float* __restrict__ out, int u, int l) {
  const int b = u >> 8, p = u & 255;
  int srow = 2 * __builtin_amdgcn_readfirstlane(unm_idx[b * RR + p]);
  const v4f* s = (const v4f*)(x + ((size_t)b * TT + srow) * CC);
  v4f* dst = (v4f*)(out + ((size_t)b * TOUT + p) * CC);
  v4f a0 = __builtin_nontemporal_load(s + l);
  v4f a1 = __builtin_nontemporal_load(s + l + 64);
  v4f a2 = __builtin_nontemporal_load(s + l + 128);
  __builtin_nontemporal_store(a0, dst + l);
  __builtin_nontemporal_store(a1, dst + l + 64);
  __builtin_nontemporal_store(a2, dst + l + 128);
}

__device__ __forceinline__ void chain_row(
    const float* __restrict__ x, const int* __restrict__ csr,
    const int* __restrict__ wd, const int* __restrict__ nchain,
    float* __restrict__ out, int s, int l) {
  const int b = s >> 8, i = s & 255;
  int nc = __builtin_amdgcn_readfirstlane(nchain[b]);
  if (i >= nc) return;
  int wv = __builtin_amdgcn_readfirstlane(wd[b * RR + i]);
  int d = wv & 511;
  int cnt = (wv >> 9) & 511;
  int off = (wv >> 18) & 511;
  v4f* dst = (v4f*)(out + ((size_t)b * TOUT + RR + d) * CC);
  v4f a0 = __builtin_nontemporal_load((const v4f*)dst + l);
  v4f a1 = __builtin_nontemporal_load((const v4f*)dst + l + 64);
  v4f a2 = __builtin_nontemporal_load((const v4f*)dst + l + 128);
  for (int j = 0; j < cnt; ++j) {
    int e = __builtin_amdgcn_readfirstlane(csr[b * RR + off + j]);
    const v4f* sx = (const v4f*)(x + ((size_t)b * TT + 2 * e) * CC);
    v4f u0 = __builtin_nontemporal_load(sx + l);
    v4f u1 = __builtin_nontemporal_load(sx + l + 64);
    v4f u2 = __builtin_nontemporal_load(sx + l + 128);
    a0 += u0; a1 += u1; a2 += u2;
  }
  __builtin_nontemporal_store(a0, dst + l);
  __builtin_nontemporal_store(a1, dst + l + 64);
  __builtin_nontemporal_store(a2, dst + l + 128);
}

__global__ __launch_bounds__(256) void gather_kernel(
    const float* __restrict__ x, const int* __restrict__ unm_idx,
    const int* __restrict__ csr, const int* __restrict__ wd,
    const int* __restrict__ nchain, float* __restrict__ out) {
  const int w = threadIdx.x >> 6;
  const int l = threadIdx.x & 63;
  if (blockIdx.x < 2048) {
    int s = blockIdx.x * 4 + w;
    chain_row(x, csr, wd, nchain, out, s, l);
    chain_row(x, csr, wd, nchain, out, s + 8192, l);
  } else {
    int u = (blockIdx.x - 2048) * 4 + w;
    unm_row(x, unm_idx, out, u, l);
    unm_row(x, unm_idx, out, u + 8192, l);
  }
}

extern "C" void kernel_launch(void* const* d_in, const int* in_sizes, int n_in,
                              void* d_out, int out_size, void* d_ws, size_t ws_size,
                              hipStream_t stream) {
  const float* x = (const float*)d_in[0];
  const float* k = (const float*)d_in[1];
  float* out = (float*)d_out;

  char* ws = (char*)d_ws;
  unsigned long long* nodekey = (unsigned long long*)(ws);  // 64*512*8 = 262144
  int* unm_idx = (int*)(ws + 262144);                       // 64*256*4 =  65536
  int* csr     = (int*)(ws + 327680);                       // 64*256*4 =  65536
  int* wd      = (int*)(ws + 393216);                       // 64*256*4 =  65536
  int* nchain  = (int*)(ws + 458752);                       // 64*4     =    256
                                                            // total 459008 B

  score_copy_kernel<<<NSCORE + NCOPY, 256, 0, stream>>>(k, x, out, nodekey);
  sort_kernel<<<BB, SS, 0, stream>>>(nodekey, unm_idx, csr, wd, nchain);
  gather_kernel<<<4096, 256, 0, stream>>>(x, unm_idx, csr, wd, nchain, out);
}

// Round 11
// 95.357 us; speedup vs baseline: 1.5899x; 1.1446x over previous
//
#include <hip/hip_runtime.h>
#include <hip/hip_bf16.h>

// Problem constants (fixed by setup_inputs): B=64, T=1024, C=768, CK=64, R=256
#define BB 64
#define TT 1024
#define CC 768
#define CKK 64
#define SS 512   // T/2
#define RR 256
#define TOUT 768 // R + S
#define ASTRIDE 68  // 64 + 4 pad: 16B-aligned, stride mod 32 = 4 -> 2-way max
#define NSCORE (BB * 8)       // 512 score blocks
#define NCOPY  (BB * SS / 4)  // 8192 copy blocks (wave per row, 4 rows/block)
#define HALFROWS (BB * TOUT / 2)  // 24576

typedef float v4f __attribute__((ext_vector_type(4)));

// ---------------------------------------------------------------------------
// Kernel 1 (fused by block range, NO cross-block sync):
//  [0, NSCORE): register-tiled max-GEMM scores[s,d]=dot(k[2s],k[2d+1]);
//    XCD-clustered (blockIdx%8 == batch%8) for B-panel L2 reuse.
//  [NSCORE, ...): dst-base copy out[b][R+d] = x[b][2d+1], wave per row.
//    x_odd loads are TEMPORAL (cached) so L3 retains them for K3's chain-base
//    re-reads; out stores NT (out is write-only for the whole pipeline).
// ---------------------------------------------------------------------------
__global__ __launch_bounds__(256) void score_copy_kernel(
    const float* __restrict__ k, const float* __restrict__ x,
    float* __restrict__ out, unsigned long long* __restrict__ nodekey) {
  const int bid = blockIdx.x;
  const int t = threadIdx.x;

  if (bid >= NSCORE) {
    const int w = t >> 6, l = t & 63;
    const int rowg = (bid - NSCORE) * 4 + w;
    const int b = rowg >> 9;
    const int d = rowg & 511;
    const v4f* s = (const v4f*)(x + ((size_t)b * TT + 2 * d + 1) * CC);
    v4f* dst = (v4f*)(out + ((size_t)b * TOUT + RR + d) * CC);
    v4f a0 = s[l];          // temporal: keep x_odd in cache for K3 base reads
    v4f a1 = s[l + 64];
    v4f a2 = s[l + 128];
    __builtin_nontemporal_store(a0, dst + l);
    __builtin_nontemporal_store(a1, dst + l + 64);
    __builtin_nontemporal_store(a2, dst + l + 128);
    return;
  }

  // score path: batch-clustered remap (bijective on [0,512))
  const int low3 = bid & 7;
  const int g = bid >> 3;
  const int rt = g & 7;
  const int b = (g >> 3) * 8 + low3;
  const int tx = t & 15, ty = t >> 4;

  __shared__ float As[64 * ASTRIDE];
  __shared__ float Bs[128 * ASTRIDE];

#pragma unroll
  for (int l = 0; l < 4; ++l) {
    int f = t + l * 256;
    int row = f >> 4, c4 = f & 15;
    float4 va = ((const float4*)(k + ((size_t)b * TT + 2 * (rt * 64 + row)) * CKK))[c4];
    *(float4*)(&As[row * ASTRIDE + c4 * 4]) = va;
  }

  unsigned long long rkey[4];
#pragma unroll
  for (int i = 0; i < 4; ++i) rkey[i] = 0ull;

  for (int ct = 0; ct < 4; ++ct) {
    __syncthreads();
#pragma unroll
    for (int l = 0; l < 8; ++l) {
      int f = t + l * 256;
      int row = f >> 4, c4 = f & 15;
      float4 vb = ((const float4*)(k + ((size_t)b * TT + 2 * (ct * 128 + row) + 1) * CKK))[c4];
      *(float4*)(&Bs[row * ASTRIDE + c4 * 4]) = vb;
    }
    __syncthreads();

    float acc[4][8];
#pragma unroll
    for (int i = 0; i < 4; ++i)
#pragma unroll
      for (int j = 0; j < 8; ++j) acc[i][j] = 0.f;

    for (int k4 = 0; k4 < 16; ++k4) {
      float4 av[4], bv[8];
#pragma unroll
      for (int i = 0; i < 4; ++i)
        av[i] = *(const float4*)(&As[(ty + 16 * i) * ASTRIDE + k4 * 4]);
#pragma unroll
      for (int j = 0; j < 8; ++j)
        bv[j] = *(const float4*)(&Bs[(tx + 16 * j) * ASTRIDE + k4 * 4]);
#pragma unroll
      for (int i = 0; i < 4; ++i)
#pragma unroll
        for (int j = 0; j < 8; ++j) {
          acc[i][j] += av[i].x * bv[j].x;
          acc[i][j] += av[i].y * bv[j].y;
          acc[i][j] += av[i].z * bv[j].z;
          acc[i][j] += av[i].w * bv[j].w;
        }
    }

#pragma unroll
    for (int i = 0; i < 4; ++i) {
      float mx = acc[i][0];
      int mj = 0;
#pragma unroll
      for (int j = 1; j < 8; ++j)
        if (acc[i][j] > mx) { mx = acc[i][j]; mj = j; }  // asc d: > keeps min d
      int d = ct * 128 + tx + 16 * mj;
      unsigned int u = __float_as_uint(mx);
      unsigned int mapped = (u & 0x80000000u) ? ~u : (u | 0x80000000u);
      unsigned long long key =
          ((unsigned long long)mapped << 32) | (unsigned int)(SS - 1 - d);
      if (key > rkey[i]) rkey[i] = key;
    }
  }

#pragma unroll
  for (int i = 0; i < 4; ++i) {
#pragma unroll
    for (int off = 1; off < 16; off <<= 1) {
      unsigned long long o = __shfl_xor(rkey[i], off);
      if (o > rkey[i]) rkey[i] = o;
    }
  }
  if (tx == 0) {
#pragma unroll
    for (int i = 0; i < 4; ++i)
      nodekey[b * SS + rt * 64 + ty + 16 * i] = rkey[i];
  }
}

// ---------------------------------------------------------------------------
// Kernel 2: per-batch stable descending argsort (hybrid bitonic: j<=32 via
// shfl_xor, j>=64 via LDS), then invert src->dst scatter into packed per-dst
// descriptor  info = cnt | e0<<9 | csr_off<<18  + CSR src array.
// (R7-proven structure.)
// ---------------------------------------------------------------------------
__global__ __launch_bounds__(512) void sort_kernel(
    const unsigned long long* __restrict__ nodekey,
    int* __restrict__ unm_idx, int* __restrict__ dstinfo,
    int* __restrict__ csr) {
  const int b = blockIdx.x;
  const int i = threadIdx.x;
  const int lane = i & 63, w = i >> 6;
  __shared__ unsigned long long key[SS];
  __shared__ int nodeidx[SS];
  __shared__ int headS[SS];
  __shared__ int nxtS[RR];
  __shared__ int eS[RR];
  __shared__ int wsum[8];

  unsigned long long nk = nodekey[b * SS + i];
  unsigned int mapped;
  int nidx;
  if (i == 0) {  // scores[:,0,:] forced to NEG_INF -> max=-1e30, argmax=0
    mapped = ~__float_as_uint(-1e30f);
    nidx = 0;
  } else {
    mapped = (unsigned int)(nk >> 32);
    nidx = SS - 1 - (int)(nk & 0xffffffffu);
  }
  nodeidx[i] = nidx;
  headS[i] = -1;
  unsigned long long my = ((unsigned long long)(~mapped) << 32) | (unsigned int)i;

  for (int kk = 2; kk <= SS; kk <<= 1) {
    for (int j = kk >> 1; j > 0; j >>= 1) {
      bool up = ((i & kk) == 0);
      bool lower = ((i & j) == 0);
      bool takeMin = (up == lower);
      unsigned long long partner;
      if (j >= 64) {
        key[i] = my;
        __syncthreads();
        partner = key[i ^ j];
        __syncthreads();
      } else {
        partner = __shfl_xor(my, j);
      }
      bool pSmaller = partner < my;
      my = (takeMin == pSmaller) ? partner : my;
    }
  }
  __syncthreads();

  int e = (int)(my & 0xffffffffu);
  if (i < RR) {
    eS[i] = e;
    int d = nodeidx[e];
    nxtS[i] = atomicExch(&headS[d], i);
  } else {
    unm_idx[b * RR + (i - RR)] = e;
  }
  __syncthreads();

  // thread i == dst row d: walk chain, count
  int cnt = 0;
  for (int it = headS[i]; it >= 0; it = nxtS[it]) ++cnt;

  // inclusive scan: wave-level shfl_up, then cross-wave partials
  int v = cnt;
#pragma unroll
  for (int o = 1; o < 64; o <<= 1) {
    int n = __shfl_up(v, o);
    if (lane >= o) v += n;
  }
  if (lane == 63) wsum[w] = v;
  __syncthreads();
  if (i == 0) {
    int run = 0;
    for (int q = 0; q < 8; ++q) { int tmp = wsum[q]; wsum[q] = run; run += tmp; }
  }
  __syncthreads();
  int off = wsum[w] + v - cnt;  // exclusive

  int j = 0;
  for (int it = headS[i]; it >= 0; it = nxtS[it]) csr[b * RR + off + (j++)] = eS[it];
  int e0 = (cnt > 0) ? eS[headS[i]] : 0;
  dstinfo[b * SS + i] = cnt | (e0 << 9) | (off << 18);
}

// ---------------------------------------------------------------------------
// Kernel 3: remainder assembly (R7 structure). Each wave processes TWO
// distant rows (MLP); 61% of dst slots early-exit on one scalar load.
//  rows [0,R):   out = x[2*unm_idx[p]]                       (NT)
//  rows [R,768): if cnt>0: out = x[2*d+1] + x[2*e0] + extra CSR rows.
//    Base row read from x (TEMPORAL — likely L3-warm from K1), not from out:
//    out is never read, x bytes identical to the K1-written base.
// ---------------------------------------------------------------------------
__device__ __forceinline__ void process_row(
    const float* __restrict__ x, const int* __restrict__ unm_idx,
    const int* __restrict__ dstinfo, const int* __restrict__ csr,
    float* __restrict__ out, int pg, int l) {
  const int b = pg / TOUT;
  const int p = pg % TOUT;
  v4f* dst = (v4f*)(out + ((size_t)b * TOUT + p) * CC);

  if (p < RR) {
    int srow = 2 * __builtin_amdgcn_readfirstlane(unm_idx[b * RR + p]);
    const v4f* s = (const v4f*)(x + ((size_t)b * TT + srow) * CC);
    v4f a0 = __builtin_nontemporal_load(s + l);
    v4f a1 = __builtin_nontemporal_load(s + l + 64);
    v4f a2 = __builtin_nontemporal_load(s + l + 128);
    __builtin_nontemporal_store(a0, dst + l);
    __builtin_nontemporal_store(a1, dst + l + 64);
    __builtin_nontemporal_store(a2, dst + l + 128);
  } else {
    int d = p - RR;
    int info = __builtin_amdgcn_readfirstlane(dstinfo[b * SS + d]);
    int cnt = info & 511;
    if (cnt == 0) return;  // base row already correct from K1
    int e0 = (info >> 9) & 511;
    int off = (info >> 18) & 511;
    const v4f* s0 = (const v4f*)(x + ((size_t)b * TT + 2 * d + 1) * CC);  // base (L3-warm)
    const v4f* s1 = (const v4f*)(x + ((size_t)b * TT + 2 * e0) * CC);
    v4f a0 = s0[l];
    v4f a1 = s0[l + 64];
    v4f a2 = s0[l + 128];
    v4f v0 = __builtin_nontemporal_load(s1 + l);
    v4f v1 = __builtin_nontemporal_load(s1 + l + 64);
    v4f v2 = __builtin_nontemporal_load(s1 + l + 128);
    a0 += v0; a1 += v1; a2 += v2;
    for (int j = 1; j < cnt; ++j) {
      int e = __builtin_amdgcn_readfirstlane(csr[b * RR + off + j]);
      const v4f* s = (const v4f*)(x + ((size_t)b * TT + 2 * e) * CC);
      v4f u0 = __builtin_nontemporal_load(s + l);
      v4f u1 = __builtin_nontemporal_load(s + l + 64);
      v4f u2 = __builtin_nontemporal_load(s + l + 128);
      a0 += u0; a1 += u1; a2 += u2;
    }
    __builtin_nontemporal_store(a0, dst + l);
    __builtin_nontemporal_store(a1, dst + l + 64);
    __builtin_nontemporal_store(a2, dst + l + 128);
  }
}

__global__ __launch_bounds__(256) void gather_kernel(
    const float* __restrict__ x, const int* __restrict__ unm_idx,
    const int* __restrict__ dstinfo, const int* __restrict__ csr,
    float* __restrict__ out) {
  const int w = threadIdx.x >> 6;
  const int l = threadIdx.x & 63;
  const int r1 = blockIdx.x * 4 + w;
  process_row(x, unm_idx, dstinfo, csr, out, r1, l);
  process_row(x, unm_idx, dstinfo, csr, out, r1 + HALFROWS, l);
}

extern "C" void kernel_launch(void* const* d_in, const int* in_sizes, int n_in,
                              void* d_out, int out_size, void* d_ws, size_t ws_size,
                              hipStream_t stream) {
  const float* x = (const float*)d_in[0];
  const float* k = (const float*)d_in[1];
  float* out = (float*)d_out;

  char* ws = (char*)d_ws;
  unsigned long long* nodekey = (unsigned long long*)(ws);  // 64*512*8 = 262144
  int* unm_idx = (int*)(ws + 262144);                       // 64*256*4 =  65536
  int* dstinfo = (int*)(ws + 327680);                       // 64*512*4 = 131072
  int* csr     = (int*)(ws + 458752);                       // 64*256*4 =  65536
                                                            // total 524288 B

  score_copy_kernel<<<NSCORE + NCOPY, 256, 0, stream>>>(k, x, out, nodekey);
  sort_kernel<<<BB, SS, 0, stream>>>(nodekey, unm_idx, dstinfo, csr);
  gather_kernel<<<HALFROWS / 4, 256, 0, stream>>>(x, unm_idx, dstinfo, csr, out);
}

// Round 12
// 95.314 us; speedup vs baseline: 1.5906x; 1.0005x over previous
//
#include <hip/hip_runtime.h>
#include <hip/hip_bf16.h>

// Problem constants (fixed by setup_inputs): B=64, T=1024, C=768, CK=64, R=256
#define BB 64
#define TT 1024
#define CC 768
#define CKK 64
#define SS 512   // T/2
#define RR 256
#define TOUT 768 // R + S
#define ASTRIDE 68  // 64 + 4 pad: 16B-aligned, stride mod 32 = 4 -> 2-way max
#define NSCORE (BB * 8)        // 512 score blocks
#define TOTROWS (BB * SS)      // 32768 dst-base copy rows
#define K1ROWS 26624           // copy rows in K1 (sized to hide score ~28µs)
#define NCOPY1 (K1ROWS / 4)    // 6656 copy blocks in K1 (4 rows each)
#define K2ROWS (TOTROWS - K1ROWS)  // 6144 rows in K2
#define NCOPY2 (K2ROWS / 8)    // 768 copy blocks in K2 (8 rows each, 512 thr)
#define HALFROWS (BB * TOUT / 2)   // 24576

typedef float v4f __attribute__((ext_vector_type(4)));

// dst-base copy of global row rowg (b = rowg/512, d = rowg%512):
// out[b][R+d] = x[b][2d+1]. Temporal x loads (L3 retains for K3 base reads),
// NT stores (out is write-only).
__device__ __forceinline__ void copy_row(const float* __restrict__ x,
                                         float* __restrict__ out,
                                         int rowg, int l) {
  const int b = rowg >> 9;
  const int d = rowg & 511;
  const v4f* s = (const v4f*)(x + ((size_t)b * TT + 2 * d + 1) * CC);
  v4f* dst = (v4f*)(out + ((size_t)b * TOUT + RR + d) * CC);
  v4f a0 = s[l];
  v4f a1 = s[l + 64];
  v4f a2 = s[l + 128];
  __builtin_nontemporal_store(a0, dst + l);
  __builtin_nontemporal_store(a1, dst + l + 64);
  __builtin_nontemporal_store(a2, dst + l + 128);
}

// ---------------------------------------------------------------------------
// Kernel 1 (fused by block range, NO cross-block sync):
//  [0, NSCORE): register-tiled max-GEMM scores[s,d]=dot(k[2s],k[2d+1]);
//    XCD-clustered (blockIdx%8 == batch%8) for B-panel L2 reuse.
//  [NSCORE, NSCORE+NCOPY1): dst-base copy rows [0, K1ROWS), wave per row.
// ---------------------------------------------------------------------------
__global__ __launch_bounds__(256) void score_copy_kernel(
    const float* __restrict__ k, const float* __restrict__ x,
    float* __restrict__ out, unsigned long long* __restrict__ nodekey) {
  const int bid = blockIdx.x;
  const int t = threadIdx.x;

  if (bid >= NSCORE) {
    const int w = t >> 6, l = t & 63;
    copy_row(x, out, (bid - NSCORE) * 4 + w, l);
    return;
  }

  // score path: batch-clustered remap (bijective on [0,512))
  const int low3 = bid & 7;
  const int g = bid >> 3;
  const int rt = g & 7;
  const int b = (g >> 3) * 8 + low3;
  const int tx = t & 15, ty = t >> 4;

  __shared__ float As[64 * ASTRIDE];
  __shared__ float Bs[128 * ASTRIDE];

#pragma unroll
  for (int l = 0; l < 4; ++l) {
    int f = t + l * 256;
    int row = f >> 4, c4 = f & 15;
    float4 va = ((const float4*)(k + ((size_t)b * TT + 2 * (rt * 64 + row)) * CKK))[c4];
    *(float4*)(&As[row * ASTRIDE + c4 * 4]) = va;
  }

  unsigned long long rkey[4];
#pragma unroll
  for (int i = 0; i < 4; ++i) rkey[i] = 0ull;

  for (int ct = 0; ct < 4; ++ct) {
    __syncthreads();
#pragma unroll
    for (int l = 0; l < 8; ++l) {
      int f = t + l * 256;
      int row = f >> 4, c4 = f & 15;
      float4 vb = ((const float4*)(k + ((size_t)b * TT + 2 * (ct * 128 + row) + 1) * CKK))[c4];
      *(float4*)(&Bs[row * ASTRIDE + c4 * 4]) = vb;
    }
    __syncthreads();

    float acc[4][8];
#pragma unroll
    for (int i = 0; i < 4; ++i)
#pragma unroll
      for (int j = 0; j < 8; ++j) acc[i][j] = 0.f;

    for (int k4 = 0; k4 < 16; ++k4) {
      float4 av[4], bv[8];
#pragma unroll
      for (int i = 0; i < 4; ++i)
        av[i] = *(const float4*)(&As[(ty + 16 * i) * ASTRIDE + k4 * 4]);
#pragma unroll
      for (int j = 0; j < 8; ++j)
        bv[j] = *(const float4*)(&Bs[(tx + 16 * j) * ASTRIDE + k4 * 4]);
#pragma unroll
      for (int i = 0; i < 4; ++i)
#pragma unroll
        for (int j = 0; j < 8; ++j) {
          acc[i][j] += av[i].x * bv[j].x;
          acc[i][j] += av[i].y * bv[j].y;
          acc[i][j] += av[i].z * bv[j].z;
          acc[i][j] += av[i].w * bv[j].w;
        }
    }

#pragma unroll
    for (int i = 0; i < 4; ++i) {
      float mx = acc[i][0];
      int mj = 0;
#pragma unroll
      for (int j = 1; j < 8; ++j)
        if (acc[i][j] > mx) { mx = acc[i][j]; mj = j; }  // asc d: > keeps min d
      int d = ct * 128 + tx + 16 * mj;
      unsigned int u = __float_as_uint(mx);
      unsigned int mapped = (u & 0x80000000u) ? ~u : (u | 0x80000000u);
      unsigned long long key =
          ((unsigned long long)mapped << 32) | (unsigned int)(SS - 1 - d);
      if (key > rkey[i]) rkey[i] = key;
    }
  }

#pragma unroll
  for (int i = 0; i < 4; ++i) {
#pragma unroll
    for (int off = 1; off < 16; off <<= 1) {
      unsigned long long o = __shfl_xor(rkey[i], off);
      if (o > rkey[i]) rkey[i] = o;
    }
  }
  if (tx == 0) {
#pragma unroll
    for (int i = 0; i < 4; ++i)
      nodekey[b * SS + rt * 64 + ty + 16 * i] = rkey[i];
  }
}

// ---------------------------------------------------------------------------
// Kernel 2 (fused): blocks [0,64): per-batch stable descending argsort
// (hybrid bitonic) + CSR inversion (R7/R11-proven). Blocks [64, 64+NCOPY2):
// remaining dst-base copy rows [K1ROWS, 32768) — BW-productive work that
// hides the sort's wall time on the other 192 CUs.
// ---------------------------------------------------------------------------
__global__ __launch_bounds__(512) void sort_copy_kernel(
    const unsigned long long* __restrict__ nodekey,
    int* __restrict__ unm_idx, int* __restrict__ dstinfo,
    int* __restrict__ csr, const float* __restrict__ x,
    float* __restrict__ out) {
  if (blockIdx.x >= BB) {
    const int w = threadIdx.x >> 6, l = threadIdx.x & 63;
    copy_row(x, out, K1ROWS + (blockIdx.x - BB) * 8 + w, l);
    return;
  }

  const int b = blockIdx.x;
  const int i = threadIdx.x;
  const int lane = i & 63, w = i >> 6;
  __shared__ unsigned long long key[SS];
  __shared__ int nodeidx[SS];
  __shared__ int headS[SS];
  __shared__ int nxtS[RR];
  __shared__ int eS[RR];
  __shared__ int wsum[8];

  unsigned long long nk = nodekey[b * SS + i];
  unsigned int mapped;
  int nidx;
  if (i == 0) {  // scores[:,0,:] forced to NEG_INF -> max=-1e30, argmax=0
    mapped = ~__float_as_uint(-1e30f);
    nidx = 0;
  } else {
    mapped = (unsigned int)(nk >> 32);
    nidx = SS - 1 - (int)(nk & 0xffffffffu);
  }
  nodeidx[i] = nidx;
  headS[i] = -1;
  unsigned long long my = ((unsigned long long)(~mapped) << 32) | (unsigned int)i;

  for (int kk = 2; kk <= SS; kk <<= 1) {
    for (int j = kk >> 1; j > 0; j >>= 1) {
      bool up = ((i & kk) == 0);
      bool lower = ((i & j) == 0);
      bool takeMin = (up == lower);
      unsigned long long partner;
      if (j >= 64) {
        key[i] = my;
        __syncthreads();
        partner = key[i ^ j];
        __syncthreads();
      } else {
        partner = __shfl_xor(my, j);
      }
      bool pSmaller = partner < my;
      my = (takeMin == pSmaller) ? partner : my;
    }
  }
  __syncthreads();

  int e = (int)(my & 0xffffffffu);
  if (i < RR) {
    eS[i] = e;
    int d = nodeidx[e];
    nxtS[i] = atomicExch(&headS[d], i);
  } else {
    unm_idx[b * RR + (i - RR)] = e;
  }
  __syncthreads();

  // thread i == dst row d: walk chain, count
  int cnt = 0;
  for (int it = headS[i]; it >= 0; it = nxtS[it]) ++cnt;

  // inclusive scan: wave-level shfl_up, then cross-wave partials
  int v = cnt;
#pragma unroll
  for (int o = 1; o < 64; o <<= 1) {
    int n = __shfl_up(v, o);
    if (lane >= o) v += n;
  }
  if (lane == 63) wsum[w] = v;
  __syncthreads();
  if (i == 0) {
    int run = 0;
    for (int q = 0; q < 8; ++q) { int tmp = wsum[q]; wsum[q] = run; run += tmp; }
  }
  __syncthreads();
  int off = wsum[w] + v - cnt;  // exclusive

  int j = 0;
  for (int it = headS[i]; it >= 0; it = nxtS[it]) csr[b * RR + off + (j++)] = eS[it];
  int e0 = (cnt > 0) ? eS[headS[i]] : 0;
  dstinfo[b * SS + i] = cnt | (e0 << 9) | (off << 18);
}

// ---------------------------------------------------------------------------
// Kernel 3: remainder assembly (R11-proven). Each wave processes TWO distant
// rows (MLP); 61% of dst slots early-exit on one scalar load.
//  rows [0,R):   out = x[2*unm_idx[p]]                       (NT)
//  rows [R,768): if cnt>0: out = x[2*d+1] + x[2*e0] + extra CSR rows.
//    Base row read from x (temporal, L3-warm from copy); out never read.
// ---------------------------------------------------------------------------
__device__ __forceinline__ void process_row(
    const float* __restrict__ x, const int* __restrict__ unm_idx,
    const int* __restrict__ dstinfo, const int* __restrict__ csr,
    float* __restrict__ out, int pg, int l) {
  const int b = pg / TOUT;
  const int p = pg % TOUT;
  v4f* dst = (v4f*)(out + ((size_t)b * TOUT + p) * CC);

  if (p < RR) {
    int srow = 2 * __builtin_amdgcn_readfirstlane(unm_idx[b * RR + p]);
    const v4f* s = (const v4f*)(x + ((size_t)b * TT + srow) * CC);
    v4f a0 = __builtin_nontemporal_load(s + l);
    v4f a1 = __builtin_nontemporal_load(s + l + 64);
    v4f a2 = __builtin_nontemporal_load(s + l + 128);
    __builtin_nontemporal_store(a0, dst + l);
    __builtin_nontemporal_store(a1, dst + l + 64);
    __builtin_nontemporal_store(a2, dst + l + 128);
  } else {
    int d = p - RR;
    int info = __builtin_amdgcn_readfirstlane(dstinfo[b * SS + d]);
    int cnt = info & 511;
    if (cnt == 0) return;  // base row already correct from copy
    int e0 = (info >> 9) & 511;
    int off = (info >> 18) & 511;
    const v4f* s0 = (const v4f*)(x + ((size_t)b * TT + 2 * d + 1) * CC);  // base
    const v4f* s1 = (const v4f*)(x + ((size_t)b * TT + 2 * e0) * CC);
    v4f a0 = s0[l];
    v4f a1 = s0[l + 64];
    v4f a2 = s0[l + 128];
    v4f v0 = __builtin_nontemporal_load(s1 + l);
    v4f v1 = __builtin_nontemporal_load(s1 + l + 64);
    v4f v2 = __builtin_nontemporal_load(s1 + l + 128);
    a0 += v0; a1 += v1; a2 += v2;
    for (int j = 1; j < cnt; ++j) {
      int e = __builtin_amdgcn_readfirstlane(csr[b * RR + off + j]);
      const v4f* s = (const v4f*)(x + ((size_t)b * TT + 2 * e) * CC);
      v4f u0 = __builtin_nontemporal_load(s + l);
      v4f u1 = __builtin_nontemporal_load(s + l + 64);
      v4f u2 = __builtin_nontemporal_load(s + l + 128);
      a0 += u0; a1 += u1; a2 += u2;
    }
    __builtin_nontemporal_store(a0, dst + l);
    __builtin_nontemporal_store(a1, dst + l + 64);
    __builtin_nontemporal_store(a2, dst + l + 128);
  }
}

__global__ __launch_bounds__(256) void gather_kernel(
    const float* __restrict__ x, const int* __restrict__ unm_idx,
    const int* __restrict__ dstinfo, const int* __restrict__ csr,
    float* __restrict__ out) {
  const int w = threadIdx.x >> 6;
  const int l = threadIdx.x & 63;
  const int r1 = blockIdx.x * 4 + w;
  process_row(x, unm_idx, dstinfo, csr, out, r1, l);
  process_row(x, unm_idx, dstinfo, csr, out, r1 + HALFROWS, l);
}

extern "C" void kernel_launch(void* const* d_in, const int* in_sizes, int n_in,
                              void* d_out, int out_size, void* d_ws, size_t ws_size,
                              hipStream_t stream) {
  const float* x = (const float*)d_in[0];
  const float* k = (const float*)d_in[1];
  float* out = (float*)d_out;

  char* ws = (char*)d_ws;
  unsigned long long* nodekey = (unsigned long long*)(ws);  // 64*512*8 = 262144
  int* unm_idx = (int*)(ws + 262144);                       // 64*256*4 =  65536
  int* dstinfo = (int*)(ws + 327680);                       // 64*512*4 = 131072
  int* csr     = (int*)(ws + 458752);                       // 64*256*4 =  65536
                                                            // total 524288 B

  score_copy_kernel<<<NSCORE + NCOPY1, 256, 0, stream>>>(k, x, out, nodekey);
  sort_copy_kernel<<<BB + NCOPY2, 512, 0, stream>>>(nodekey, unm_idx, dstinfo,
                                                    csr, x, out);
  gather_kernel<<<HALFROWS / 4, 256, 0, stream>>>(x, unm_idx, dstinfo, csr, out);
}